// Round 3
// baseline (343.480 us; speedup 1.0000x reference)
//
#include <hip/hip_runtime.h>
#include <cmath>

typedef _Float16 f16;
typedef _Float16 f16x8 __attribute__((ext_vector_type(8)));
typedef float    f32x4 __attribute__((ext_vector_type(4)));
typedef float    f32x16 __attribute__((ext_vector_type(16)));
typedef unsigned short u16;
typedef unsigned int   u32;
typedef u16 us8 __attribute__((ext_vector_type(8)));
typedef u16 us4 __attribute__((ext_vector_type(4)));

#define MFMA16(a, b, c) __builtin_amdgcn_mfma_f32_16x16x32_f16((a), (b), (c), 0, 0, 0)
#define MFMA32(a, b, c) __builtin_amdgcn_mfma_f32_32x32x16_f16((a), (b), (c), 0, 0, 0)

__device__ __forceinline__ void gload_lds16(const void* g, void* l) {
    __builtin_amdgcn_global_load_lds((const __attribute__((address_space(1))) void*)g,
                                     (__attribute__((address_space(3))) void*)l, 16, 0, 0);
}

// ---------------- elementwise f32 -> f16 cast (8 elems / thread) ----------------
__global__ void castk(const float* __restrict__ src, f16* __restrict__ dst, int n8) {
    int i = blockIdx.x * 256 + threadIdx.x;
    if (i >= n8) return;
    const float4* s = (const float4*)src + (size_t)i * 2;
    float4 a = s[0], b = s[1];
    union { f16 h[8]; us8 v; } o;
    o.h[0] = (f16)a.x; o.h[1] = (f16)a.y; o.h[2] = (f16)a.z; o.h[3] = (f16)a.w;
    o.h[4] = (f16)b.x; o.h[5] = (f16)b.y; o.h[6] = (f16)b.z; o.h[7] = (f16)b.w;
    *(us8*)&dst[(size_t)i * 8] = o.v;
}

// ---------------- per-batch transpose+cast: O[b][s][h] f32 -> OT[b][h][s] f16 ----
__global__ void transpose_cast(const float* __restrict__ O, f16* __restrict__ OT) {
    __shared__ f16 tbuf[64][68];
    int bid = blockIdx.x;
    int b = bid >> 8, t = bid & 255;
    int s0 = (t & 31) * 64, h0 = (t >> 5) * 64;
    const float* Ob = O + (size_t)b * 2048 * 512;
    f16* OTb = OT + (size_t)b * 512 * 2048;
    int tid = threadIdx.x;
    int rr = tid >> 4, cc = (tid & 15) * 4;
#pragma unroll
    for (int i = 0; i < 4; ++i) {
        int r = rr + 16 * i;
        float4 v = *(const float4*)&Ob[(size_t)(s0 + r) * 512 + h0 + cc];
        tbuf[r][cc + 0] = (f16)v.x; tbuf[r][cc + 1] = (f16)v.y;
        tbuf[r][cc + 2] = (f16)v.z; tbuf[r][cc + 3] = (f16)v.w;
    }
    __syncthreads();
#pragma unroll
    for (int i = 0; i < 4; ++i) {
        int hr = rr + 16 * i;
        union { f16 h[4]; us4 v; } pk;
        pk.h[0] = tbuf[cc + 0][hr]; pk.h[1] = tbuf[cc + 1][hr];
        pk.h[2] = tbuf[cc + 2][hr]; pk.h[3] = tbuf[cc + 3][hr];
        *(us4*)&OTb[(size_t)(h0 + hr) * 2048 + s0 + cc] = pk.v;
    }
}

// ---------------- GEMM1: Qf16 = tanh(Of16 * Wf16^T + bias) ----------------------
__global__ __launch_bounds__(256) void gemm1(const f16* __restrict__ A,
                                             const f16* __restrict__ W,
                                             const float* __restrict__ bias,
                                             f16* __restrict__ Qo) {
    __shared__ f16 lA[128 * 32];
    __shared__ f16 lB[128 * 32];
    const int tid = threadIdx.x;
    const int lane = tid & 63, w = tid >> 6;
    const int wm = w >> 1, wn = w & 1;
    const int bm = blockIdx.x >> 2, bn = blockIdx.x & 3;
    const int r0 = bm * 128, c0 = bn * 128;
    const int l15 = lane & 15, g = lane >> 4;
    f32x4 acc[4][4] = {};
    for (int kt = 0; kt < 16; ++kt) {
        int k0 = kt * 32;
        __syncthreads();
#pragma unroll
        for (int i = 0; i < 2; ++i) {
            int slot = i * 256 + tid;
            int row = slot >> 2, oct = slot & 3;
            int soct = oct ^ (row & 3);
            *(us8*)&lA[slot * 8] = *(const us8*)&A[(size_t)(r0 + row) * 512 + k0 + soct * 8];
            *(us8*)&lB[slot * 8] = *(const us8*)&W[(size_t)(c0 + row) * 512 + k0 + soct * 8];
        }
        __syncthreads();
        f16x8 af[4], bf[4];
#pragma unroll
        for (int mf = 0; mf < 4; ++mf) {
            int row = 64 * wm + 16 * mf + l15;
            int oct = g ^ (row & 3);
            af[mf] = *(const f16x8*)&lA[(row * 4 + oct) * 8];
        }
#pragma unroll
        for (int nf = 0; nf < 4; ++nf) {
            int row = 64 * wn + 16 * nf + l15;
            int oct = g ^ (row & 3);
            bf[nf] = *(const f16x8*)&lB[(row * 4 + oct) * 8];
        }
#pragma unroll
        for (int mf = 0; mf < 4; ++mf)
#pragma unroll
            for (int nf = 0; nf < 4; ++nf)
                acc[mf][nf] = MFMA16(af[mf], bf[nf], acc[mf][nf]);
    }
    float bv[4];
#pragma unroll
    for (int nf = 0; nf < 4; ++nf) bv[nf] = bias[c0 + 64 * wn + 16 * nf + l15];
#pragma unroll
    for (int mf = 0; mf < 4; ++mf) {
#pragma unroll
        for (int nf = 0; nf < 4; ++nf) {
#pragma unroll
            for (int r = 0; r < 4; ++r) {
                float y = tanhf(acc[mf][nf][r] + bv[nf]);
                int row = r0 + 64 * wm + 16 * mf + 4 * g + r;
                int col = c0 + 64 * wn + 16 * nf + l15;
                Qo[(size_t)row * 512 + col] = (f16)y;
            }
        }
    }
}

// ---------------- fused attention (32x32 MFMA, 4 waves x (32q, 256h)) -----------
// Grid: 256 blocks (b = blk&7 -> XCD-pinned batch, qt = blk>>3, q0 = 64*qt).
// Wave w: q-half (w&1), h-half (w>>1). S^T = K*Q^T (32x32 tiles, q on lane&31).
// K tile [32t][512k], V^T tile [512h][32t], both double-buffered via global_load_lds.
__global__ __launch_bounds__(256, 1) void attn(const f16* __restrict__ Qf,
                                               const f16* __restrict__ Of,
                                               const f16* __restrict__ OfT,
                                               float* __restrict__ Out) {
    extern __shared__ __align__(16) char smem[];  // 131072: 2 x {K 32KB, V 32KB}
    const int tid = threadIdx.x;
    const int lane = tid & 63, w = tid >> 6;
    const int l31 = lane & 31, hi5 = lane >> 5;
    const int qh = w & 1, hh = w >> 1;
    const int b = blockIdx.x & 7, qt = blockIdx.x >> 3;
    const int q0 = qt * 64;
    const int q = q0 + 32 * qh + l31;
    const f16* Ob  = Of  + (size_t)b * 2048 * 512;
    const f16* OTb = OfT + (size_t)b * 512 * 2048;

    // Q B-fragments: B[k][n]: n = l31 = q, k = 16*ks + 8*hi5 + j
    f16x8 qf[32];
    const f16* qrow = Qf + ((size_t)b * 2048 + q) * 512;
#pragma unroll
    for (int ks = 0; ks < 32; ++ks) qf[ks] = *(const f16x8*)&qrow[ks * 16 + hi5 * 8];

    float m = -INFINITY, lsum = 0.f;
    f32x16 acc[8] = {};

    auto STAGE = [&](int buf, int t0) {
        f16* lK = (f16*)(smem + buf * 65536);
        f16* lV = (f16*)(smem + buf * 65536 + 32768);
#pragma unroll
        for (int i = 0; i < 8; ++i) {
            int slot = i * 256 + tid;
            int t = slot >> 6, oct = slot & 63;
            gload_lds16(&Ob[(size_t)(t0 + t) * 512 + (oct ^ (t & 7)) * 8], &lK[slot * 8]);
        }
#pragma unroll
        for (int i = 0; i < 8; ++i) {
            int slot = i * 256 + tid;
            int h = slot >> 2, oct = slot & 3;
            gload_lds16(&OTb[(size_t)h * 2048 + t0 + (oct ^ ((h >> 1) & 3)) * 8], &lV[slot * 8]);
        }
    };

    STAGE(0, 0);
    STAGE(1, 32);

    for (int kt = 0; kt < 64; ++kt) {
        const int cur = kt & 1;
        if (kt < 63) asm volatile("s_waitcnt vmcnt(16)" ::: "memory");
        else         asm volatile("s_waitcnt vmcnt(0)"  ::: "memory");
        __builtin_amdgcn_s_barrier();

        const f16* lK = (const f16*)(smem + cur * 65536);
        const f16* lV = (const f16*)(smem + cur * 65536 + 32768);

        // QK^T: S^T[32t][32q], 32 k-steps of 16, 4 independent chains
        f32x16 sa0 = {}, sa1 = {}, sa2 = {}, sa3 = {};
        const int tsw = l31 & 7;
#pragma unroll
        for (int ks = 0; ks < 32; ks += 4) {
            f16x8 k0 = *(const f16x8*)&lK[(l31 * 64 + ((2 * (ks + 0) + hi5) ^ tsw)) * 8];
            f16x8 k1 = *(const f16x8*)&lK[(l31 * 64 + ((2 * (ks + 1) + hi5) ^ tsw)) * 8];
            f16x8 k2 = *(const f16x8*)&lK[(l31 * 64 + ((2 * (ks + 2) + hi5) ^ tsw)) * 8];
            f16x8 k3 = *(const f16x8*)&lK[(l31 * 64 + ((2 * (ks + 3) + hi5) ^ tsw)) * 8];
            sa0 = MFMA32(k0, qf[ks + 0], sa0);
            sa1 = MFMA32(k1, qf[ks + 1], sa1);
            sa2 = MFMA32(k2, qf[ks + 2], sa2);
            sa3 = MFMA32(k3, qf[ks + 3], sa3);
        }
        sa0 += sa1; sa2 += sa3;
        f32x16 sv = sa0 + sa2;

        // online softmax over t (lane pair l, l^32 share q = l31); defer-max THR=8
        float tmax = sv[0];
#pragma unroll
        for (int i = 1; i < 16; ++i) tmax = fmaxf(tmax, sv[i]);
        tmax = fmaxf(tmax, __shfl_xor(tmax, 32));
        if (__any(tmax > m + 8.0f)) {
            float mnew = fmaxf(m, tmax);
            float corr = __expf(m - mnew);
            m = mnew;
            lsum *= corr;
#pragma unroll
            for (int hf = 0; hf < 8; ++hf) acc[hf] *= corr;
        }
        float p[16];
        float ps = 0.f;
#pragma unroll
        for (int i = 0; i < 16; ++i) { p[i] = __expf(sv[i] - m); ps += p[i]; }
        ps += __shfl_xor(ps, 32);
        lsum += ps;

        // pack p into 8 f16-pair words (word i = regs 2i, 2i+1)
        u32 wd[8];
#pragma unroll
        for (int i = 0; i < 8; ++i) {
            union { f16 h[2]; u32 u; } x;
            x.h[0] = (f16)p[2 * i]; x.h[1] = (f16)p[2 * i + 1];
            wd[i] = x.u;
        }
        // lane-half exchange: half0 needs partner's w0,w1 (frag0) / w4,w5 (frag1);
        // half1 needs partner's w2,w3 / w6,w7.
        const bool Hh = (hi5 != 0);
        u32 e0 = (u32)__shfl_xor((int)(Hh ? wd[0] : wd[2]), 32);
        u32 e1 = (u32)__shfl_xor((int)(Hh ? wd[1] : wd[3]), 32);
        u32 e2 = (u32)__shfl_xor((int)(Hh ? wd[4] : wd[6]), 32);
        u32 e3 = (u32)__shfl_xor((int)(Hh ? wd[5] : wd[7]), 32);
        union { u32 u[4]; f16x8 v; } f0_, f1_;
        f0_.u[0] = Hh ? e0 : wd[0];  f0_.u[1] = Hh ? e1 : wd[1];
        f0_.u[2] = Hh ? wd[2] : e0;  f0_.u[3] = Hh ? wd[3] : e1;
        f1_.u[0] = Hh ? e2 : wd[4];  f1_.u[1] = Hh ? e3 : wd[5];
        f1_.u[2] = Hh ? wd[6] : e2;  f1_.u[3] = Hh ? wd[7] : e3;
        f16x8 pf0 = f0_.v, pf1 = f1_.v;

        // PV: D[32h tile][32q] += V^T[h][t] * P[t][q], 8 h-tiles x 2 k-steps
#pragma unroll
        for (int hf = 0; hf < 8; ++hf) {
            int h = 256 * hh + 32 * hf + l31;
            int sw = (h >> 1) & 3;
            f16x8 v0 = *(const f16x8*)&lV[(h * 4 + (hi5 ^ sw)) * 8];
            f16x8 v1 = *(const f16x8*)&lV[(h * 4 + ((2 + hi5) ^ sw)) * 8];
            acc[hf] = MFMA32(v0, pf0, acc[hf]);
            acc[hf] = MFMA32(v1, pf1, acc[hf]);
        }

        __builtin_amdgcn_s_barrier();
        if (kt + 2 < 64) STAGE(cur, (kt + 2) * 32);
    }

    // epilogue: normalize, direct float4 stores (C rows are 4-contiguous in h)
    float inv = 1.0f / lsum;
    const size_t orow = ((size_t)b * 2048 + q) * 512;
#pragma unroll
    for (int hf = 0; hf < 8; ++hf) {
#pragma unroll
        for (int r2 = 0; r2 < 4; ++r2) {
            float4 o;
            o.x = acc[hf][4 * r2 + 0] * inv;
            o.y = acc[hf][4 * r2 + 1] * inv;
            o.z = acc[hf][4 * r2 + 2] * inv;
            o.w = acc[hf][4 * r2 + 3] * inv;
            int h0 = 256 * hh + 32 * hf + 8 * r2 + 4 * hi5;
            *(float4*)&Out[orow + h0] = o;
        }
    }
}

extern "C" void kernel_launch(void* const* d_in, const int* in_sizes, int n_in,
                              void* d_out, int out_size, void* d_ws, size_t ws_size,
                              hipStream_t stream) {
    const float* O  = (const float*)d_in[0];
    const float* Ww = (const float*)d_in[1];
    const float* Wb = (const float*)d_in[2];
    float* Out = (float*)d_out;
    char* ws = (char*)d_ws;
    f16* Of16 = (f16*)ws;                           // 16 MB
    f16* OT   = (f16*)(ws + ((size_t)16 << 20));    // 16 MB
    f16* Qf   = (f16*)(ws + ((size_t)32 << 20));    // 16 MB
    f16* Wf   = (f16*)(ws + ((size_t)48 << 20));    // 512 KB

    hipFuncSetAttribute((const void*)attn, hipFuncAttributeMaxDynamicSharedMemorySize, 131072);

    castk<<<4096, 256, 0, stream>>>(O, Of16, 1048576);
    castk<<<128, 256, 0, stream>>>(Ww, Wf, 32768);
    transpose_cast<<<2048, 256, 0, stream>>>(O, OT);
    gemm1<<<512, 256, 0, stream>>>(Of16, Wf, Wb, Qf);
    attn<<<256, 256, 131072, stream>>>(Qf, Of16, OT, Out);
}